// Round 1
// baseline (11802.944 us; speedup 1.0000x reference)
//
#include <hip/hip_runtime.h>

#define DEG 17
#define NSTEPS 32
#define HD 96
#define EE 16
#define BB 16
#define NN 64
#define NODES (BB*NN)   // 1024
#define MPB 4           // nodes per block
#define DPAD 20         // padded DEG stride (16B-aligned float4 chunks)

// ---------------- init: embedding + input MLP -> xin ----------------
__global__ void init_kernel(
    const int* __restrict__ x,
    const float* __restrict__ digit_emb,
    const float* __restrict__ row_emb,
    const float* __restrict__ col_emb,
    const float* __restrict__ in0_W,
    const float* __restrict__ in0_b,
    const float* __restrict__ in_Ws,
    const float* __restrict__ in_bs,
    float* __restrict__ xin)
{
  const int node = blockIdx.x;
  const int j = threadIdx.x;
  const int n = node & 63;
  const int r = n >> 3, c = n & 7;
  __shared__ float feat[3*EE];
  __shared__ float za[HD];
  __shared__ float zb[HD];
  if (j < EE)        feat[j] = digit_emb[x[node]*EE + j];
  else if (j < 2*EE) feat[j] = row_emb[r*EE + (j-EE)];
  else if (j < 3*EE) feat[j] = col_emb[c*EE + (j-2*EE)];
  __syncthreads();
  float a = in0_b[j];
  for (int k = 0; k < 3*EE; ++k) a = fmaf(feat[k], in0_W[k*HD + j], a);
  za[j] = fmaxf(a, 0.f);
  __syncthreads();
  a = in_bs[j];
  for (int k = 0; k < HD; ++k) a = fmaf(za[k], in_Ws[k*HD + j], a);
  zb[j] = fmaxf(a, 0.f);
  __syncthreads();
  a = in_bs[HD + j];
  for (int k = 0; k < HD; ++k) a = fmaf(zb[k], in_Ws[9216 + k*HD + j], a);
  za[j] = fmaxf(a, 0.f);
  __syncthreads();
  a = in_bs[2*HD + j];
  for (int k = 0; k < HD; ++k) a = fmaf(za[k], in_Ws[2*9216 + k*HD + j], a);
  xin[node*HD + j] = a;
}

// ---------------- one recurrent step ----------------
// u layout per node: [0..95] = h @ msg0_W[0:96]   (edge contribution)
//                    [96..191] = h @ msg0_W[96:192] (self contribution)
__global__ __launch_bounds__(MPB*HD) void step_kernel(
    const float* __restrict__ u_prev, float* __restrict__ u_next,
    float* __restrict__ h, float* __restrict__ s,
    const float* __restrict__ xin,
    const int* __restrict__ edges,
    const float* __restrict__ msg0_W, const float* __restrict__ msg0_b,
    const float* __restrict__ msg_Ws, const float* __restrict__ msg_bs,
    const float* __restrict__ W_ih, const float* __restrict__ W_hh,
    const float* __restrict__ b_ih, const float* __restrict__ b_hh,
    const float* __restrict__ pred_W, const float* __restrict__ pred_b,
    const int* __restrict__ target,
    float* __restrict__ loss_acc, int* __restrict__ cnt,
    float* __restrict__ final_pred_out, int step)
{
  __shared__ float z1s[MPB][HD][DPAD];  // [k][d] layout
  __shared__ float z2s[MPB][HD][DPAD];
  __shared__ float act[MPB][HD];
  __shared__ float lgts[MPB][8];

  const int t = threadIdx.x;
  const int m = t / HD;
  const int j = t - m*HD;
  const int node = blockIdx.x * MPB + m;
  const int b = node >> 6;
  const int n = node & 63;

  // ---- z1 for 17 edges: relu(u_edge[nbr] + u_self[self] + b0)
  {
    const float us  = u_prev[node*192 + 96 + j];
    const float b0j = msg0_b[j];
    #pragma unroll
    for (int d = 0; d < DEG; ++d) {
      const int nbr = edges[n*DEG + d];
      const float ue = u_prev[((b<<6) + nbr)*192 + j];
      z1s[m][j][d] = fmaxf(ue + us + b0j, 0.f);
    }
  }
  __syncthreads();

  // ---- layer1: z2_d = relu(z1_d @ W1 + b1), 17 accumulators per thread
  {
    const float* __restrict__ W1 = msg_Ws;
    float acc[DEG];
    #pragma unroll
    for (int d = 0; d < DEG; ++d) acc[d] = 0.f;
    for (int k = 0; k < HD; ++k) {
      const float w = W1[k*HD + j];
      const float* zk = &z1s[m][k][0];
      const float4 q0 = *(const float4*)(zk);
      const float4 q1 = *(const float4*)(zk+4);
      const float4 q2 = *(const float4*)(zk+8);
      const float4 q3 = *(const float4*)(zk+12);
      const float z16 = zk[16];
      acc[0]=fmaf(q0.x,w,acc[0]); acc[1]=fmaf(q0.y,w,acc[1]); acc[2]=fmaf(q0.z,w,acc[2]); acc[3]=fmaf(q0.w,w,acc[3]);
      acc[4]=fmaf(q1.x,w,acc[4]); acc[5]=fmaf(q1.y,w,acc[5]); acc[6]=fmaf(q1.z,w,acc[6]); acc[7]=fmaf(q1.w,w,acc[7]);
      acc[8]=fmaf(q2.x,w,acc[8]); acc[9]=fmaf(q2.y,w,acc[9]); acc[10]=fmaf(q2.z,w,acc[10]); acc[11]=fmaf(q2.w,w,acc[11]);
      acc[12]=fmaf(q3.x,w,acc[12]); acc[13]=fmaf(q3.y,w,acc[13]); acc[14]=fmaf(q3.z,w,acc[14]); acc[15]=fmaf(q3.w,w,acc[15]);
      acc[16]=fmaf(z16,w,acc[16]);
    }
    const float b1j = msg_bs[j];
    #pragma unroll
    for (int d = 0; d < DEG; ++d) z2s[m][j][d] = fmaxf(acc[d] + b1j, 0.f);
  }
  __syncthreads();

  // ---- layer2 + relu + sum over d -> z3sum
  {
    const float* __restrict__ W2 = msg_Ws + 9216;
    float acc[DEG];
    #pragma unroll
    for (int d = 0; d < DEG; ++d) acc[d] = 0.f;
    for (int k = 0; k < HD; ++k) {
      const float w = W2[k*HD + j];
      const float* zk = &z2s[m][k][0];
      const float4 q0 = *(const float4*)(zk);
      const float4 q1 = *(const float4*)(zk+4);
      const float4 q2 = *(const float4*)(zk+8);
      const float4 q3 = *(const float4*)(zk+12);
      const float z16 = zk[16];
      acc[0]=fmaf(q0.x,w,acc[0]); acc[1]=fmaf(q0.y,w,acc[1]); acc[2]=fmaf(q0.z,w,acc[2]); acc[3]=fmaf(q0.w,w,acc[3]);
      acc[4]=fmaf(q1.x,w,acc[4]); acc[5]=fmaf(q1.y,w,acc[5]); acc[6]=fmaf(q1.z,w,acc[6]); acc[7]=fmaf(q1.w,w,acc[7]);
      acc[8]=fmaf(q2.x,w,acc[8]); acc[9]=fmaf(q2.y,w,acc[9]); acc[10]=fmaf(q2.z,w,acc[10]); acc[11]=fmaf(q2.w,w,acc[11]);
      acc[12]=fmaf(q3.x,w,acc[12]); acc[13]=fmaf(q3.y,w,acc[13]); acc[14]=fmaf(q3.z,w,acc[14]); acc[15]=fmaf(q3.w,w,acc[15]);
      acc[16]=fmaf(z16,w,acc[16]);
    }
    const float b2j = msg_bs[HD + j];
    float z3 = 0.f;
    #pragma unroll
    for (int d = 0; d < DEG; ++d) z3 += fmaxf(acc[d] + b2j, 0.f);
    act[m][j] = z3;
  }
  __syncthreads();

  // ---- layer3 (linear, summed): msg = z3sum @ W3 + 17*b3
  float msg;
  {
    const float* __restrict__ W3 = msg_Ws + 2*9216;
    float a = 17.f * msg_bs[2*HD + j];
    for (int k = 0; k < HD; k += 4) {
      const float4 q = *(const float4*)&act[m][k];
      float qa[4]; *(float4*)qa = q;
      #pragma unroll
      for (int kk = 0; kk < 4; ++kk)
        a = fmaf(qa[kk], W3[(k+kk)*HD + j], a);
    }
    msg = a;
  }
  __syncthreads();

  // ---- LSTM gates: [msg|xin] @ W_ih + h @ W_hh + b_ih + b_hh
  float g0 = b_ih[j]        + b_hh[j];
  float g1 = b_ih[HD + j]   + b_hh[HD + j];
  float g2 = b_ih[2*HD + j] + b_hh[2*HD + j];
  float g3 = b_ih[3*HD + j] + b_hh[3*HD + j];

  act[m][j] = msg;
  __syncthreads();
  for (int k = 0; k < HD; k += 4) {
    const float4 q = *(const float4*)&act[m][k];
    float qa[4]; *(float4*)qa = q;
    #pragma unroll
    for (int kk = 0; kk < 4; ++kk) {
      const float* wr = W_ih + (k+kk)*384 + j;
      g0 = fmaf(qa[kk], wr[0], g0);
      g1 = fmaf(qa[kk], wr[HD], g1);
      g2 = fmaf(qa[kk], wr[2*HD], g2);
      g3 = fmaf(qa[kk], wr[3*HD], g3);
    }
  }
  __syncthreads();
  act[m][j] = xin[node*HD + j];
  __syncthreads();
  for (int k = 0; k < HD; k += 4) {
    const float4 q = *(const float4*)&act[m][k];
    float qa[4]; *(float4*)qa = q;
    #pragma unroll
    for (int kk = 0; kk < 4; ++kk) {
      const float* wr = W_ih + (96+k+kk)*384 + j;
      g0 = fmaf(qa[kk], wr[0], g0);
      g1 = fmaf(qa[kk], wr[HD], g1);
      g2 = fmaf(qa[kk], wr[2*HD], g2);
      g3 = fmaf(qa[kk], wr[3*HD], g3);
    }
  }
  __syncthreads();
  act[m][j] = h[node*HD + j];
  __syncthreads();
  for (int k = 0; k < HD; k += 4) {
    const float4 q = *(const float4*)&act[m][k];
    float qa[4]; *(float4*)qa = q;
    #pragma unroll
    for (int kk = 0; kk < 4; ++kk) {
      const float* wr = W_hh + (k+kk)*384 + j;
      g0 = fmaf(qa[kk], wr[0], g0);
      g1 = fmaf(qa[kk], wr[HD], g1);
      g2 = fmaf(qa[kk], wr[2*HD], g2);
      g3 = fmaf(qa[kk], wr[3*HD], g3);
    }
  }

  // ---- pointwise LSTM update
  const float sv = s[node*HD + j];
  const float ig = 1.f/(1.f + expf(-g0));
  const float fg = 1.f/(1.f + expf(-g1));
  const float gg = tanhf(g2);
  const float og = 1.f/(1.f + expf(-g3));
  const float s2 = fg*sv + ig*gg;
  const float h2 = og*tanhf(s2);
  s[node*HD + j] = s2;
  h[node*HD + j] = h2;
  __syncthreads();
  act[m][j] = h2;
  __syncthreads();

  // ---- u_next = h2 @ [W0_edge | W0_self]
  {
    float ue = 0.f, usf = 0.f;
    for (int k = 0; k < HD; k += 4) {
      const float4 q = *(const float4*)&act[m][k];
      float qa[4]; *(float4*)qa = q;
      #pragma unroll
      for (int kk = 0; kk < 4; ++kk) {
        ue  = fmaf(qa[kk], msg0_W[(k+kk)*HD + j], ue);
        usf = fmaf(qa[kk], msg0_W[(96+k+kk)*HD + j], usf);
      }
    }
    u_next[node*192 + j] = ue;
    u_next[node*192 + 96 + j] = usf;
  }

  // ---- prediction head / loss / acc
  if (j < 8) {
    float lg = pred_b[j];
    for (int k = 0; k < HD; ++k) lg = fmaf(act[m][k], pred_W[k*8 + j], lg);
    lgts[m][j] = lg;
  }
  __syncthreads();
  if (j == 0) {
    float best = lgts[m][0];
    int pred = 0;
    float mx = best;
    #pragma unroll
    for (int c = 1; c < 8; ++c) {
      const float v = lgts[m][c];
      if (v > best) { best = v; pred = c; }
      if (v > mx) mx = v;
    }
    float sum = 0.f;
    #pragma unroll
    for (int c = 0; c < 8; ++c) sum += expf(lgts[m][c] - mx);
    const float lse = mx + logf(sum);
    const int tgt = target[node] - 1;
    const float lp = lgts[m][tgt] - lse;
    atomicAdd(loss_acc, -lp);
    if (pred == tgt) atomicAdd(&cnt[step*BB + b], 1);
    if (step == NSTEPS-1) final_pred_out[node] = (float)pred;
  }
}

// ---------------- finalize: accs + loss ----------------
__global__ void finalize_kernel(const float* __restrict__ loss_acc,
                                const int* __restrict__ cnt,
                                float* __restrict__ out)
{
  const int t = threadIdx.x;
  if (t < NSTEPS) {
    int c = 0;
    for (int bb = 0; bb < BB; ++bb) c += (cnt[t*BB + bb] == NN) ? 1 : 0;
    out[1 + t] = (float)c / (float)BB;
  }
  if (t == 0) out[0] = loss_acc[0] / ((float)NODES * (float)NSTEPS);
}

extern "C" void kernel_launch(void* const* d_in, const int* in_sizes, int n_in,
                              void* d_out, int out_size, void* d_ws, size_t ws_size,
                              hipStream_t stream) {
  const int*   x         = (const int*)  d_in[0];
  const int*   target    = (const int*)  d_in[1];
  const int*   edges     = (const int*)  d_in[2];
  const float* digit_emb = (const float*)d_in[3];
  const float* row_emb   = (const float*)d_in[4];
  const float* col_emb   = (const float*)d_in[5];
  const float* in0_W     = (const float*)d_in[6];
  const float* in0_b     = (const float*)d_in[7];
  const float* in_Ws     = (const float*)d_in[8];
  const float* in_bs     = (const float*)d_in[9];
  const float* msg0_W    = (const float*)d_in[10];
  const float* msg0_b    = (const float*)d_in[11];
  const float* msg_Ws    = (const float*)d_in[12];
  const float* msg_bs    = (const float*)d_in[13];
  const float* W_ih      = (const float*)d_in[14];
  const float* W_hh      = (const float*)d_in[15];
  const float* b_ih      = (const float*)d_in[16];
  const float* b_hh      = (const float*)d_in[17];
  const float* pred_W    = (const float*)d_in[18];
  const float* pred_b    = (const float*)d_in[19];

  float* ws   = (float*)d_ws;
  float* hbuf = ws;                   // 1024*96
  float* sbuf = ws + 98304;           // 1024*96
  float* u0   = ws + 196608;          // 1024*192
  float* u1   = ws + 393216;          // 1024*192
  float* lossp= ws + 589824;          // 1 (padded)
  int*   cnt  = (int*)(ws + 589840);  // 32*16 ints
  float* xin  = ws + 590352;          // 1024*96

  // zero h, s, u0, u1, loss, cnt (ws is poisoned 0xAA before every launch)
  hipMemsetAsync(d_ws, 0, 590352*sizeof(float), stream);

  init_kernel<<<NODES, HD, 0, stream>>>(x, digit_emb, row_emb, col_emb,
                                        in0_W, in0_b, in_Ws, in_bs, xin);

  float* outp = (float*)d_out;
  for (int st = 0; st < NSTEPS; ++st) {
    const float* up = (st & 1) ? u1 : u0;
    float*       un = (st & 1) ? u0 : u1;
    step_kernel<<<NODES/MPB, MPB*HD, 0, stream>>>(
        up, un, hbuf, sbuf, xin, edges,
        msg0_W, msg0_b, msg_Ws, msg_bs,
        W_ih, W_hh, b_ih, b_hh, pred_W, pred_b,
        target, lossp, cnt, outp + 1 + NSTEPS, st);
  }

  finalize_kernel<<<1, 64, 0, stream>>>(lossp, cnt, outp);
}

// Round 2
// 1172.446 us; speedup vs baseline: 10.0669x; 10.0669x over previous
//
#include <hip/hip_runtime.h>

#define DEG 17
#define NSTEPS 32
#define HD 96
#define BB 16
#define NN 64
#define NODES (BB*NN)   // 1024
#define Z1STR 80        // 4 nodes * 20 padded rows; stride 80 (2-way bank = free)
#define Z2STR 84        // padded for 4-way-max write conflicts, 16B-aligned reads

// ws float offsets
#define WS_H      0
#define WS_S      98304
#define WS_U0     196608
#define WS_U1     393216
#define WS_XIN    590352
#define WS_GX     688656
#define WS_W1P    1081872
#define WS_W2P    1094160
#define WS_LOSSP  1106448
#define WS_CNTP   1114640   // ints

// ---------------- init0: pad W1/W2 to [96][128] (16B-aligned 8-groups of 6 cols)
__global__ void wpad_kernel(const float* __restrict__ msg_Ws,
                            float* __restrict__ W1p, float* __restrict__ W2p)
{
  const int k = blockIdx.x;        // 0..95
  const int tid = threadIdx.x;     // 0..127
  const int jg = tid >> 3, jj = tid & 7;
  float v1 = 0.f, v2 = 0.f;
  if (jj < 6) {
    v1 = msg_Ws[k*96 + jg*6 + jj];
    v2 = msg_Ws[9216 + k*96 + jg*6 + jj];
  }
  W1p[k*128 + tid] = v1;
  W2p[k*128 + tid] = v2;
}

// ---------------- init1: embedding + input MLP -> xin (one-time)
__global__ void init_kernel(
    const int* __restrict__ x,
    const float* __restrict__ digit_emb,
    const float* __restrict__ row_emb,
    const float* __restrict__ col_emb,
    const float* __restrict__ in0_W,
    const float* __restrict__ in0_b,
    const float* __restrict__ in_Ws,
    const float* __restrict__ in_bs,
    float* __restrict__ xin)
{
  const int node = blockIdx.x;
  const int j = threadIdx.x;
  const int n = node & 63;
  const int r = n >> 3, c = n & 7;
  __shared__ float feat[48];
  __shared__ float za[HD];
  __shared__ float zb[HD];
  if (j < 16)      feat[j] = digit_emb[x[node]*16 + j];
  else if (j < 32) feat[j] = row_emb[r*16 + (j-16)];
  else if (j < 48) feat[j] = col_emb[c*16 + (j-32)];
  __syncthreads();
  float a = in0_b[j];
  for (int k = 0; k < 48; ++k) a = fmaf(feat[k], in0_W[k*HD + j], a);
  za[j] = fmaxf(a, 0.f);
  __syncthreads();
  a = in_bs[j];
  for (int k = 0; k < HD; ++k) a = fmaf(za[k], in_Ws[k*HD + j], a);
  zb[j] = fmaxf(a, 0.f);
  __syncthreads();
  a = in_bs[HD + j];
  for (int k = 0; k < HD; ++k) a = fmaf(zb[k], in_Ws[9216 + k*HD + j], a);
  za[j] = fmaxf(a, 0.f);
  __syncthreads();
  a = in_bs[2*HD + j];
  for (int k = 0; k < HD; ++k) a = fmaf(za[k], in_Ws[2*9216 + k*HD + j], a);
  xin[node*HD + j] = a;
}

// ---------------- init2: gx = xin @ W_ih[96:192] + b_ih + b_hh (one-time)
__global__ __launch_bounds__(384) void gx_kernel(
    const float* __restrict__ xin, const float* __restrict__ W_ih,
    const float* __restrict__ b_ih, const float* __restrict__ b_hh,
    float* __restrict__ gx)
{
  __shared__ float xs[4*HD];
  const int tid = threadIdx.x;
  const int base = blockIdx.x * 4;
  {
    const int m = tid / HD, k = tid - m*HD;
    xs[m*HD + k] = xin[(base+m)*HD + k];
  }
  __syncthreads();
  const int j = tid;  // 0..383
  float a0 = b_ih[j] + b_hh[j], a1 = a0, a2 = a0, a3 = a0;
  for (int k = 0; k < HD; ++k) {
    const float w = W_ih[(96+k)*384 + j];
    a0 = fmaf(xs[k], w, a0);
    a1 = fmaf(xs[HD+k], w, a1);
    a2 = fmaf(xs[2*HD+k], w, a2);
    a3 = fmaf(xs[3*HD+k], w, a3);
  }
  gx[(base+0)*384 + j] = a0;
  gx[(base+1)*384 + j] = a1;
  gx[(base+2)*384 + j] = a2;
  gx[(base+3)*384 + j] = a3;
}

// ---------------- one recurrent step ----------------
__global__ __launch_bounds__(384) void step_kernel(
    const float* __restrict__ u_prev, float* __restrict__ u_next,
    float* __restrict__ h, float* __restrict__ s,
    const float* __restrict__ gx,
    const int* __restrict__ edges,
    const float* __restrict__ W1p, const float* __restrict__ W2p,
    const float* __restrict__ msg0_W, const float* __restrict__ msg0_b,
    const float* __restrict__ msg_Ws, const float* __restrict__ msg_bs,
    const float* __restrict__ W_ih, const float* __restrict__ W_hh,
    const float* __restrict__ pred_W, const float* __restrict__ pred_b,
    const int* __restrict__ target,
    float* __restrict__ lossP, int* __restrict__ cntP,
    float* __restrict__ final_pred_out, int step)
{
  __shared__ float sm[15744];            // 62976 B
  float* const z1s = sm;                 // [96][80]
  float* const z2s = sm + 7680;          // [96][84]
  // overlays of z1s region (dead after GEMM1):
  float* const s3t   = sm;               // [96][4]
  float* const msgh  = sm + 384;         // [192][4]  (k-major, m-minor)
  float* const h2t   = sm + 1152;        // [96][4]
  float* const lgt   = sm + 1536;        // 32
  float* const gates = sm + 1568;        // [4][384]
  float* const P3    = sm + 3104;        // [8][4][96]
  // overlays of z2s region (dead after GEMM2):
  float* const PL = z2s;                 // [4][4][384]
  float* const PU = z2s;                 // [8][4][192]

  const int tid = threadIdx.x;
  const int blk = blockIdx.x;
  const int base = blk * 4;              // first node of block
  const int bb = blk >> 4;               // batch index
  const int nbase = (blk & 15) * 4;      // node-in-batch of m=0

  // ===== phase 1: build z1 rows (+ zero dummy rows 17..19 per node) =====
  {
    const int m = tid / HD, k = tid - m*HD;
    const float usv = u_prev[(base+m)*192 + 96 + k];
    const float b0v = msg0_b[k];
    z1s[k*Z1STR + m*20 + 17] = 0.f;
    z1s[k*Z1STR + m*20 + 18] = 0.f;
    z1s[k*Z1STR + m*20 + 19] = 0.f;
    const int erow = (nbase + m) * DEG;
    #pragma unroll 1
    for (int r = 0; r < DEG; ++r) {
      const int nbr = edges[erow + r];
      const float ue = u_prev[(bb*64 + nbr)*192 + k];
      z1s[k*Z1STR + m*20 + r] = fmaxf(ue + usv + b0v, 0.f);
    }
  }
  __syncthreads();

  // ===== phase 2: GEMM1  z2 = relu(z1 @ W1 + b1)  (80x96 @ 96x96) =====
  if (tid < 320) {
    const int jg = tid & 15, dg = tid >> 4;
    const int j6 = jg*6, j8 = jg*8, dg4 = dg*4;
    float acc[4][6];
    #pragma unroll
    for (int dd = 0; dd < 4; ++dd)
      #pragma unroll
      for (int jj = 0; jj < 6; ++jj) acc[dd][jj] = 0.f;
    #pragma unroll 4
    for (int k = 0; k < HD; ++k) {
      const float4 z = *(const float4*)&z1s[k*Z1STR + dg4];
      const float* wp = W1p + k*128 + j8;
      const float4 wa = *(const float4*)wp;
      const float2 wb = *(const float2*)(wp + 4);
      const float ze[4] = {z.x, z.y, z.z, z.w};
      const float we[6] = {wa.x, wa.y, wa.z, wa.w, wb.x, wb.y};
      #pragma unroll
      for (int dd = 0; dd < 4; ++dd)
        #pragma unroll
        for (int jj = 0; jj < 6; ++jj)
          acc[dd][jj] = fmaf(ze[dd], we[jj], acc[dd][jj]);
    }
    #pragma unroll
    for (int jj = 0; jj < 6; ++jj) {
      const float b1 = msg_bs[j6 + jj];
      float4 q;
      q.x = fmaxf(acc[0][jj] + b1, 0.f);
      q.y = fmaxf(acc[1][jj] + b1, 0.f);
      q.z = fmaxf(acc[2][jj] + b1, 0.f);
      q.w = fmaxf(acc[3][jj] + b1, 0.f);
      *(float4*)&z2s[(j6+jj)*Z2STR + dg4] = q;
    }
  }
  __syncthreads();

  // ===== phase 2.5: zero s3t, stage h-part of msgh =====
  {
    s3t[tid] = 0.f;
    const int m = tid / HD, k = tid - m*HD;
    msgh[(96+k)*4 + m] = h[(base+m)*HD + k];
  }
  __syncthreads();

  // ===== phase 3: GEMM2 + relu + masked row-sum -> s3t[k][m] =====
  if (tid < 320) {
    const int jg = tid & 15, dg = tid >> 4;
    const int j6 = jg*6, j8 = jg*8, dg4 = dg*4;
    const int nd = dg / 5, dgl = dg - nd*5;
    float acc[4][6];
    #pragma unroll
    for (int dd = 0; dd < 4; ++dd)
      #pragma unroll
      for (int jj = 0; jj < 6; ++jj) acc[dd][jj] = 0.f;
    #pragma unroll 4
    for (int k = 0; k < HD; ++k) {
      const float4 z = *(const float4*)&z2s[k*Z2STR + dg4];
      const float* wp = W2p + k*128 + j8;
      const float4 wa = *(const float4*)wp;
      const float2 wb = *(const float2*)(wp + 4);
      const float ze[4] = {z.x, z.y, z.z, z.w};
      const float we[6] = {wa.x, wa.y, wa.z, wa.w, wb.x, wb.y};
      #pragma unroll
      for (int dd = 0; dd < 4; ++dd)
        #pragma unroll
        for (int jj = 0; jj < 6; ++jj)
          acc[dd][jj] = fmaf(ze[dd], we[jj], acc[dd][jj]);
    }
    const int nvalid = (dgl < 4) ? 4 : 1;  // rows 0..16 valid of 20
    #pragma unroll
    for (int jj = 0; jj < 6; ++jj) {
      const float b2 = msg_bs[96 + j6 + jj];
      float p = 0.f;
      #pragma unroll
      for (int dd = 0; dd < 4; ++dd)
        if (dd < nvalid) p += fmaxf(acc[dd][jj] + b2, 0.f);
      atomicAdd(&s3t[(j6+jj)*4 + nd], p);
    }
  }
  __syncthreads();

  // ===== phase 4: GEMM3  msg = s3 @ W3 + 17*b3  -> msgh[k<96][m] =====
  if (tid < 192) {
    const int jg = tid % 24, kq = tid / 24;   // kq 0..7, 12 k each
    const int j4 = jg*4, k0 = kq*12;
    const float* W3 = msg_Ws + 2*9216;
    float acc[4][4];
    #pragma unroll
    for (int m = 0; m < 4; ++m)
      #pragma unroll
      for (int jj = 0; jj < 4; ++jj) acc[m][jj] = 0.f;
    #pragma unroll 4
    for (int kk = 0; kk < 12; ++kk) {
      const int k = k0 + kk;
      const float4 sv = *(const float4*)&s3t[k*4];
      const float4 wv = *(const float4*)&W3[k*96 + j4];
      const float se[4] = {sv.x, sv.y, sv.z, sv.w};
      const float we[4] = {wv.x, wv.y, wv.z, wv.w};
      #pragma unroll
      for (int m = 0; m < 4; ++m)
        #pragma unroll
        for (int jj = 0; jj < 4; ++jj)
          acc[m][jj] = fmaf(se[m], we[jj], acc[m][jj]);
    }
    #pragma unroll
    for (int m = 0; m < 4; ++m) {
      float4 q = {acc[m][0], acc[m][1], acc[m][2], acc[m][3]};
      *(float4*)&P3[(kq*4 + m)*96 + j4] = q;
    }
  }
  __syncthreads();
  {
    const int m = tid / HD, j = tid - m*HD;
    float v = 17.f * msg_bs[192 + j];
    #pragma unroll
    for (int kq = 0; kq < 8; ++kq) v += P3[(kq*4 + m)*96 + j];
    msgh[j*4 + m] = v;
  }
  __syncthreads();

  // ===== phase 5: LSTM GEMM  gates = [msg|h] @ [Wih;Whh] + gx =====
  if (tid < 192) {
    const int jg = tid % 48, kq = tid / 48;   // kq 0..3, 48 k each
    const int j8 = jg*8, k0 = kq*48;
    const float* Wb = (kq < 2) ? (W_ih + j8) : (W_hh + j8 - 96*384);
    float acc[4][8];
    #pragma unroll
    for (int m = 0; m < 4; ++m)
      #pragma unroll
      for (int jj = 0; jj < 8; ++jj) acc[m][jj] = 0.f;
    #pragma unroll 2
    for (int k = k0; k < k0 + 48; ++k) {
      const float4 iv = *(const float4*)&msgh[k*4];
      const float* wp = Wb + k*384;
      const float4 wa = *(const float4*)wp;
      const float4 wc = *(const float4*)(wp + 4);
      const float ie[4] = {iv.x, iv.y, iv.z, iv.w};
      const float we[8] = {wa.x, wa.y, wa.z, wa.w, wc.x, wc.y, wc.z, wc.w};
      #pragma unroll
      for (int m = 0; m < 4; ++m)
        #pragma unroll
        for (int jj = 0; jj < 8; ++jj)
          acc[m][jj] = fmaf(ie[m], we[jj], acc[m][jj]);
    }
    #pragma unroll
    for (int m = 0; m < 4; ++m) {
      float4 qa = {acc[m][0], acc[m][1], acc[m][2], acc[m][3]};
      float4 qb = {acc[m][4], acc[m][5], acc[m][6], acc[m][7]};
      *(float4*)&PL[(kq*4 + m)*384 + j8] = qa;
      *(float4*)&PL[(kq*4 + m)*384 + j8 + 4] = qb;
    }
  }
  __syncthreads();
  {
    const int j = tid;
    #pragma unroll
    for (int m = 0; m < 4; ++m) {
      float g = gx[(base+m)*384 + j];
      #pragma unroll
      for (int kq = 0; kq < 4; ++kq) g += PL[(kq*4 + m)*384 + j];
      gates[m*384 + j] = g;
    }
  }
  __syncthreads();

  // ===== phase 6: pointwise LSTM =====
  {
    const int m = tid / HD, hj = tid - m*HD;
    const int node = base + m;
    const float gi = gates[m*384 + hj];
    const float gf = gates[m*384 + 96 + hj];
    const float gg = gates[m*384 + 192 + hj];
    const float go = gates[m*384 + 288 + hj];
    const float sv = s[node*HD + hj];
    const float ig = 1.f/(1.f + expf(-gi));
    const float fg = 1.f/(1.f + expf(-gf));
    const float cg = tanhf(gg);
    const float og = 1.f/(1.f + expf(-go));
    const float s2 = fg*sv + ig*cg;
    const float h2 = og*tanhf(s2);
    s[node*HD + hj] = s2;
    h[node*HD + hj] = h2;
    h2t[hj*4 + m] = h2;
  }
  __syncthreads();

  // ===== phase 7: u_next = h2 @ [W0_edge | W0_self]  (4x96 @ 96x192) =====
  if (tid < 192) {
    const int jg = tid % 24, kq = tid / 24;   // kq 0..7, 12 k each
    const int j8 = jg*8, k0 = kq*12;
    const float* Wb = (j8 < 96) ? (msg0_W + j8) : (msg0_W + 9216 + j8 - 96);
    float acc[4][8];
    #pragma unroll
    for (int m = 0; m < 4; ++m)
      #pragma unroll
      for (int jj = 0; jj < 8; ++jj) acc[m][jj] = 0.f;
    #pragma unroll 4
    for (int kk = 0; kk < 12; ++kk) {
      const int k = k0 + kk;
      const float4 iv = *(const float4*)&h2t[k*4];
      const float* wp = Wb + k*96;
      const float4 wa = *(const float4*)wp;
      const float4 wc = *(const float4*)(wp + 4);
      const float ie[4] = {iv.x, iv.y, iv.z, iv.w};
      const float we[8] = {wa.x, wa.y, wa.z, wa.w, wc.x, wc.y, wc.z, wc.w};
      #pragma unroll
      for (int m = 0; m < 4; ++m)
        #pragma unroll
        for (int jj = 0; jj < 8; ++jj)
          acc[m][jj] = fmaf(ie[m], we[jj], acc[m][jj]);
    }
    #pragma unroll
    for (int m = 0; m < 4; ++m) {
      float4 qa = {acc[m][0], acc[m][1], acc[m][2], acc[m][3]};
      float4 qb = {acc[m][4], acc[m][5], acc[m][6], acc[m][7]};
      *(float4*)&PU[(kq*4 + m)*192 + j8] = qa;
      *(float4*)&PU[(kq*4 + m)*192 + j8 + 4] = qb;
    }
  }
  __syncthreads();
  {
    const int j = tid % 192, mh = tid / 192;  // mh 0..1
    #pragma unroll
    for (int t = 0; t < 2; ++t) {
      const int mm = mh + 2*t;
      float v = 0.f;
      #pragma unroll
      for (int kq = 0; kq < 8; ++kq) v += PU[(kq*4 + mm)*192 + j];
      u_next[(base+mm)*192 + j] = v;
    }
  }

  // ===== phase 8: prediction head =====
  if (tid < 256) {
    const int m = tid >> 6, c = (tid >> 3) & 7, kq = tid & 7;
    float p = 0.f;
    #pragma unroll
    for (int kk = 0; kk < 12; ++kk) {
      const int k = kq*12 + kk;
      p = fmaf(h2t[k*4 + m], pred_W[k*8 + c], p);
    }
    p += __shfl_xor(p, 1);
    p += __shfl_xor(p, 2);
    p += __shfl_xor(p, 4);
    if (kq == 0) lgt[m*8 + c] = p + pred_b[c];
  }
  __syncthreads();
  if (tid < 4) {
    const int m = tid;
    const int node = base + m;
    float mx = lgt[m*8];
    int pred = 0;
    #pragma unroll
    for (int c = 1; c < 8; ++c) {
      const float v = lgt[m*8 + c];
      if (v > mx) { mx = v; pred = c; }
    }
    float sum = 0.f;
    #pragma unroll
    for (int c = 0; c < 8; ++c) sum += expf(lgt[m*8 + c] - mx);
    const float lse = mx + logf(sum);
    const int tgt = target[node] - 1;
    lgt[16 + m] = lse - lgt[m*8 + tgt];      // -logp
    lgt[20 + m] = (pred == tgt) ? 1.f : 0.f;
    if (step == NSTEPS-1) final_pred_out[node] = (float)pred;
    if (m == 0) {
      // lanes 0..3 of this wave wrote above; in-wave order + waitcnt make this safe
      lossP[step*256 + blk] = lgt[16] + lgt[17] + lgt[18] + lgt[19];
      cntP[step*256 + blk] = (int)(lgt[20] + lgt[21] + lgt[22] + lgt[23]);
    }
  }
}

// ---------------- finalize: accs + loss ----------------
__global__ void finalize_kernel(const float* __restrict__ lossP,
                                const int* __restrict__ cntP,
                                float* __restrict__ out)
{
  __shared__ float sl[32];
  const int tid = threadIdx.x;   // 256
  const int st = tid >> 3, q = tid & 7;
  float lsum = 0.f;
  for (int i = 0; i < 32; ++i) lsum += lossP[st*256 + q*32 + i];
  lsum += __shfl_xor(lsum, 1);
  lsum += __shfl_xor(lsum, 2);
  lsum += __shfl_xor(lsum, 4);
  if (q == 0) sl[st] = lsum;
  float okc = 0.f;
  #pragma unroll
  for (int t = 0; t < 2; ++t) {
    const int bbat = q + 8*t;
    int c = 0;
    for (int i = 0; i < 16; ++i) c += cntP[st*256 + bbat*16 + i];
    okc += (c == 64) ? 1.f : 0.f;
  }
  okc += __shfl_xor(okc, 1);
  okc += __shfl_xor(okc, 2);
  okc += __shfl_xor(okc, 4);
  if (q == 0) out[1 + st] = okc / 16.f;
  __syncthreads();
  if (tid == 0) {
    float tot = 0.f;
    for (int i = 0; i < 32; ++i) tot += sl[i];
    out[0] = tot / ((float)NODES * (float)NSTEPS);
  }
}

extern "C" void kernel_launch(void* const* d_in, const int* in_sizes, int n_in,
                              void* d_out, int out_size, void* d_ws, size_t ws_size,
                              hipStream_t stream) {
  const int*   x         = (const int*)  d_in[0];
  const int*   target    = (const int*)  d_in[1];
  const int*   edges     = (const int*)  d_in[2];
  const float* digit_emb = (const float*)d_in[3];
  const float* row_emb   = (const float*)d_in[4];
  const float* col_emb   = (const float*)d_in[5];
  const float* in0_W     = (const float*)d_in[6];
  const float* in0_b     = (const float*)d_in[7];
  const float* in_Ws     = (const float*)d_in[8];
  const float* in_bs     = (const float*)d_in[9];
  const float* msg0_W    = (const float*)d_in[10];
  const float* msg0_b    = (const float*)d_in[11];
  const float* msg_Ws    = (const float*)d_in[12];
  const float* msg_bs    = (const float*)d_in[13];
  const float* W_ih      = (const float*)d_in[14];
  const float* W_hh      = (const float*)d_in[15];
  const float* pred_W    = (const float*)d_in[18];
  const float* pred_b    = (const float*)d_in[19];

  float* ws    = (float*)d_ws;
  float* hbuf  = ws + WS_H;
  float* sbuf  = ws + WS_S;
  float* u0    = ws + WS_U0;
  float* u1    = ws + WS_U1;
  float* xin   = ws + WS_XIN;
  float* gxb   = ws + WS_GX;
  float* W1p   = ws + WS_W1P;
  float* W2p   = ws + WS_W2P;
  float* lossP = ws + WS_LOSSP;
  int*   cntP  = (int*)(ws + WS_CNTP);

  // zero h, s, u0 (u1/lossP/cntP fully written each call)
  hipMemsetAsync(d_ws, 0, (size_t)393216*sizeof(float), stream);

  wpad_kernel<<<96, 128, 0, stream>>>(msg_Ws, W1p, W2p);
  init_kernel<<<NODES, HD, 0, stream>>>(x, digit_emb, row_emb, col_emb,
                                        in0_W, in0_b, in_Ws, in_bs, xin);
  gx_kernel<<<256, 384, 0, stream>>>(xin, W_ih,
                                     (const float*)d_in[16], (const float*)d_in[17],
                                     gxb);

  float* outp = (float*)d_out;
  for (int st = 0; st < NSTEPS; ++st) {
    const float* up = (st & 1) ? u1 : u0;
    float*       un = (st & 1) ? u0 : u1;
    step_kernel<<<256, 384, 0, stream>>>(
        up, un, hbuf, sbuf, gxb, edges,
        W1p, W2p, msg0_W, msg0_b, msg_Ws, msg_bs,
        W_ih, W_hh, pred_W, pred_b,
        target, lossP, cntP, outp + 1 + NSTEPS, st);
  }

  finalize_kernel<<<1, 256, 0, stream>>>(lossP, cntP, outp);
}